// Round 1
// baseline (506.526 us; speedup 1.0000x reference)
//
#include <hip/hip_runtime.h>

typedef __bf16 bf16;
typedef __bf16 bf16x8 __attribute__((ext_vector_type(8)));
typedef float f32x4 __attribute__((ext_vector_type(4)));
typedef float f32x16 __attribute__((ext_vector_type(16)));

// async global->LDS, 16B per lane; LDS dest is wave-uniform base + lane*16
__device__ __forceinline__ void gl_lds16(const bf16* g, bf16* l) {
  __builtin_amdgcn_global_load_lds(
      (__attribute__((address_space(1))) void*)g,
      (__attribute__((address_space(3))) void*)l, 16, 0, 0);
}

// ---------------- fp32 -> bf16 convert, 8 elems/thread ----------------
__global__ __launch_bounds__(256) void cvt_f32_bf16(
    const float* __restrict__ src, bf16* __restrict__ dst, int n8) {
  int i = blockIdx.x * 256 + threadIdx.x;
  if (i >= n8) return;
  const float4* s4 = (const float4*)src;
  float4 a = s4[2 * i], b = s4[2 * i + 1];
  bf16x8 o = {(bf16)a.x, (bf16)a.y, (bf16)a.z, (bf16)a.w,
              (bf16)b.x, (bf16)b.y, (bf16)b.z, (bf16)b.w};
  *(bf16x8*)(dst + (size_t)i * 8) = o;
}

// ------- V [2048,1024] f32 -> VT [1024,2048] bf16, per batch ----------
__global__ __launch_bounds__(256) void transpose_v(
    const float* __restrict__ V, bf16* __restrict__ VT) {
  int b = blockIdx.z;
  const float* Vb = V + (size_t)b * 2048 * 1024;
  bf16* Tb = VT + (size_t)b * 1024 * 2048;
  __shared__ float tile[32][33];  // +1 pad: conflict-free transposed read
  int tx = threadIdx.x, ty = threadIdx.y;
  int x = blockIdx.x * 32 + tx;
  int yb = blockIdx.y * 32;
#pragma unroll
  for (int j = 0; j < 4; j++)
    tile[ty + j * 8][tx] = Vb[(size_t)(yb + ty + j * 8) * 1024 + x];
  __syncthreads();
  int xo = yb + tx;
#pragma unroll
  for (int j = 0; j < 4; j++)
    Tb[(size_t)(blockIdx.x * 32 + ty + j * 8) * 2048 + xo] =
        (bf16)tile[tx][ty + j * 8];
}

// ================= 256x256 ring-pipelined MFMA GEMM ===================
// C = A[M,K] * Bm[N,K]^T, bf16 in, 32x32x16 MFMA.
// 512 thr = 8 waves (2M x 4N), 128x64 per wave, acc[4][2] f32x16.
// LDS: 4-slot ring of K=32 slices, each A[256x32]+B[256x32] bf16 = 32KB
//   -> 128KB total. Slice s lives in region s&3.
// Schedule (T3+T4): while computing slice s (2 phases, 8 MFMA each),
//   issue 4 global_load_lds staging slice s+3 into region (s-1)&3 (freed
//   by the boundary barrier). Boundary per slice: s_waitcnt vmcnt(8)
//   (leaves slices s+1,s+2 in flight; proves slice s landed) + raw
//   s_barrier. NEVER vmcnt(0) in the main loop. Tail: vmcnt 4 -> 0.
// Swizzle (T2): LDS[row][slot] = G[row][slot ^ (row&3)], granule = 8 bf16.
//   Read side XORs the same key -> <=2-way bank aliasing (free, m136).
//   Staging pre-swizzles the GLOBAL granule per lane (dest stays linear,
//   as global_load_lds requires).
// MODE 0: C bf16 = acc + bias[col]            (projection)
// MODE 1: C bf16 = mask[col] ? acc/32 : -1e9  (QK^T scores)
// MODE 2: C f32  = acc                        (PV output)
template <int MODE>
__global__ __launch_bounds__(512, 2) void gemm256(
    const bf16* __restrict__ A, const bf16* __restrict__ Bm,
    void* __restrict__ Cv, const float* __restrict__ bias,
    const int* __restrict__ mask, int M, int N, int K,
    long long sA, long long sB, long long sC) {
  const int b = blockIdx.z;
  const bf16* Ab = A + (long long)b * sA;
  const bf16* Bb = Bm + (long long)b * sB;

  // T1: XCD-aware swizzle over the xy tile grid (nwg % 8 == 0 by launch).
  const int nx = gridDim.x, nwg = nx * gridDim.y;
  const int orig = blockIdx.y * nx + blockIdx.x;
  const int swz = (orig & 7) * (nwg >> 3) + (orig >> 3);
  const int m0 = (swz / nx) * 256, n0 = (swz % nx) * 256;

  __shared__ __align__(16) bf16 lds[4][2][256 * 32];  // [ring][A/B][tile]

  const int tid = threadIdx.x, w = tid >> 6, lane = tid & 63;
  const int wr = w >> 2, wc = w & 3;  // wave grid 2x4
  const int fr = lane & 31;           // frag row within 32-tile
  const int fh = lane >> 5;           // k-granule half
  const int key = lane & 3;           // read-side swizzle key (== row&3)
  const bf16* Aq = Ab + (long long)m0 * K;
  const bf16* Bq = Bb + (long long)n0 * K;

  f32x16 acc[4][2];
#pragma unroll
  for (int i = 0; i < 4; i++)
#pragma unroll
    for (int j = 0; j < 2; j++)
#pragma unroll
      for (int r = 0; r < 16; r++) acc[i][j][r] = 0.f;

  // stage part p (rows p*128..p*128+127) of slice t: 2 gload_lds / thread
  const int srow = lane >> 2;                       // 16 rows / wave-instr
  const int sgsw = ((lane & 3) ^ (srow & 3)) * 8;   // pre-swizzled granule
  auto stage_part = [&](int t, int p) {
    const int rg = t & 3;
    const int row = p * 128 + w * 16 + srow;
    const long long gc = (long long)t * 32 + sgsw;
    const int dbase = (p * 128 + w * 16) * 32;      // wave-uniform
    gl_lds16(Aq + (long long)row * K + gc, &lds[rg][0][dbase]);
    gl_lds16(Bq + (long long)row * K + gc, &lds[rg][1][dbase]);
  };

  auto do_slice = [&](int s, bool stg) {
    const int rg = s & 3;
    // ---- phase 0: A frags + B(ni=0), stage part 0, MFMA ni=0 ----
    bf16x8 af[4][2], bfr[2];
#pragma unroll
    for (int mi = 0; mi < 4; mi++)
#pragma unroll
      for (int ks = 0; ks < 2; ks++) {
        const int row = wr * 128 + mi * 32 + fr;
        const int slot = (ks * 2 + fh) ^ key;
        af[mi][ks] = *(const bf16x8*)&lds[rg][0][row * 32 + slot * 8];
      }
#pragma unroll
    for (int ks = 0; ks < 2; ks++) {
      const int row = wc * 64 + fr;
      const int slot = (ks * 2 + fh) ^ key;
      bfr[ks] = *(const bf16x8*)&lds[rg][1][row * 32 + slot * 8];
    }
    if (stg) stage_part(s + 3, 0);
    __builtin_amdgcn_s_setprio(1);
#pragma unroll
    for (int mi = 0; mi < 4; mi++)
#pragma unroll
      for (int ks = 0; ks < 2; ks++)
        acc[mi][0] = __builtin_amdgcn_mfma_f32_32x32x16_bf16(
            af[mi][ks], bfr[ks], acc[mi][0], 0, 0, 0);
    __builtin_amdgcn_s_setprio(0);
    // ---- phase 1: B(ni=1), stage part 1, MFMA ni=1 ----
#pragma unroll
    for (int ks = 0; ks < 2; ks++) {
      const int row = wc * 64 + 32 + fr;
      const int slot = (ks * 2 + fh) ^ key;
      bfr[ks] = *(const bf16x8*)&lds[rg][1][row * 32 + slot * 8];
    }
    if (stg) stage_part(s + 3, 1);
    __builtin_amdgcn_s_setprio(1);
#pragma unroll
    for (int mi = 0; mi < 4; mi++)
#pragma unroll
      for (int ks = 0; ks < 2; ks++)
        acc[mi][1] = __builtin_amdgcn_mfma_f32_32x32x16_bf16(
            af[mi][ks], bfr[ks], acc[mi][1], 0, 0, 0);
    __builtin_amdgcn_s_setprio(0);
  };

  const int NS = K >> 5;  // K=32 slices; NS >= 3, even
  // prologue: stage slices 0,1,2 (12 vmem instrs / wave)
  stage_part(0, 0); stage_part(0, 1);
  stage_part(1, 0); stage_part(1, 1);
  stage_part(2, 0); stage_part(2, 1);

  for (int s = 0; s < NS - 2; ++s) {
    asm volatile("s_waitcnt vmcnt(8)" ::: "memory");  // slice s landed
    __builtin_amdgcn_s_barrier();
    do_slice(s, s + 3 < NS);
  }
  asm volatile("s_waitcnt vmcnt(4)" ::: "memory");
  __builtin_amdgcn_s_barrier();
  do_slice(NS - 2, false);
  asm volatile("s_waitcnt vmcnt(0)" ::: "memory");
  __builtin_amdgcn_s_barrier();
  do_slice(NS - 1, false);

  // C/D layout (m74/m101-verified): col=lane&31,
  // row = (reg&3) + 8*(reg>>2) + 4*(lane>>5)
  const int ecol = lane & 31, er4 = (lane >> 5) * 4;
  if constexpr (MODE == 0) {
    bf16* C = (bf16*)Cv;
#pragma unroll
    for (int ni = 0; ni < 2; ni++) {
      int col = n0 + wc * 64 + ni * 32 + ecol;
      float bv = bias[col];
#pragma unroll
      for (int mi = 0; mi < 4; mi++)
#pragma unroll
        for (int r = 0; r < 16; r++) {
          int row = m0 + wr * 128 + mi * 32 + er4 + (r & 3) + 8 * (r >> 2);
          C[(long long)row * N + col] = (bf16)(acc[mi][ni][r] + bv);
        }
    }
  } else if constexpr (MODE == 1) {
    bf16* C = (bf16*)Cv + (long long)b * sC;
    const int* mb = mask + b * 2048;
#pragma unroll
    for (int ni = 0; ni < 2; ni++) {
      int col = n0 + wc * 64 + ni * 32 + ecol;
      bool keep = mb[col] != 0;
#pragma unroll
      for (int mi = 0; mi < 4; mi++)
#pragma unroll
        for (int r = 0; r < 16; r++) {
          int row = m0 + wr * 128 + mi * 32 + er4 + (r & 3) + 8 * (r >> 2);
          C[(long long)row * N + col] =
              keep ? (bf16)(acc[mi][ni][r] * 0.03125f) : (bf16)(-1e9f);
        }
    }
  } else {
    float* C = (float*)Cv + (long long)b * sC;
#pragma unroll
    for (int ni = 0; ni < 2; ni++) {
      int col = n0 + wc * 64 + ni * 32 + ecol;
#pragma unroll
      for (int mi = 0; mi < 4; mi++)
#pragma unroll
        for (int r = 0; r < 16; r++) {
          int row = m0 + wr * 128 + mi * 32 + er4 + (r & 3) + 8 * (r >> 2);
          C[(long long)row * N + col] = acc[mi][ni][r];
        }
    }
  }
}

// ------------- row softmax: S bf16 [.,2048] -> P bf16 -----------------
__global__ __launch_bounds__(256) void softmax_rows(
    const bf16* __restrict__ S, bf16* __restrict__ P) {
  long long row = blockIdx.x;
  const bf16x8* src = (const bf16x8*)(S + row * 2048);
  int tid = threadIdx.x, w = tid >> 6, lane = tid & 63;
  bf16x8 v = src[tid];
  float f[8];
#pragma unroll
  for (int i = 0; i < 8; i++) f[i] = (float)v[i];
  float m = f[0];
#pragma unroll
  for (int i = 1; i < 8; i++) m = fmaxf(m, f[i]);
#pragma unroll
  for (int off = 32; off; off >>= 1) m = fmaxf(m, __shfl_xor(m, off, 64));
  __shared__ float redm[4], reds[4];
  if (lane == 0) redm[w] = m;
  __syncthreads();
  m = fmaxf(fmaxf(redm[0], redm[1]), fmaxf(redm[2], redm[3]));
  float e[8], s = 0.f;
#pragma unroll
  for (int i = 0; i < 8; i++) {
    e[i] = __expf(f[i] - m);
    s += e[i];
  }
#pragma unroll
  for (int off = 32; off; off >>= 1) s += __shfl_xor(s, off, 64);
  if (lane == 0) reds[w] = s;
  __syncthreads();
  s = reds[0] + reds[1] + reds[2] + reds[3];
  float inv = 1.0f / s;
  bf16x8 o;
#pragma unroll
  for (int i = 0; i < 8; i++) o[i] = (bf16)(e[i] * inv);
  *(bf16x8*)(P + row * 2048 + tid * 8) = o;
}

extern "C" void kernel_launch(void* const* d_in, const int* in_sizes, int n_in,
                              void* d_out, int out_size, void* d_ws,
                              size_t ws_size, hipStream_t stream) {
  const float* query = (const float*)d_in[0];
  const float* key_in = (const float*)d_in[1];
  const float* value = (const float*)d_in[2];
  const int* mask = (const int*)d_in[3];
  const float* Wq_w = (const float*)d_in[4];
  const float* Wq_b = (const float*)d_in[5];
  const float* Wk_w = (const float*)d_in[6];
  const float* Wk_b = (const float*)d_in[7];
  float* out = (float*)d_out;

  // workspace layout (224 MB), regions time-shared:
  //  [0,128MB):  qx(32) kx(32) wq(2) wk(2)  -> then S bf16 (64)
  //  [128,192MB): qp(32) kp(32)             -> then P bf16 (64)
  //  [192,224MB): vt bf16 (32)
  const size_t MB = 1ull << 20;
  char* base = (char*)d_ws;
  bf16* qx = (bf16*)(base + 0 * MB);
  bf16* kx = (bf16*)(base + 32 * MB);
  bf16* wq = (bf16*)(base + 64 * MB);
  bf16* wk = (bf16*)(base + 66 * MB);
  bf16* S = (bf16*)(base + 0 * MB);
  bf16* qp = (bf16*)(base + 128 * MB);
  bf16* kp = (bf16*)(base + 160 * MB);
  bf16* P = (bf16*)(base + 128 * MB);
  bf16* vt = (bf16*)(base + 192 * MB);

  cvt_f32_bf16<<<8192, 256, 0, stream>>>(query, qx, 2097152);
  cvt_f32_bf16<<<8192, 256, 0, stream>>>(key_in, kx, 2097152);
  cvt_f32_bf16<<<512, 256, 0, stream>>>(Wq_w, wq, 131072);
  cvt_f32_bf16<<<512, 256, 0, stream>>>(Wk_w, wk, 131072);
  transpose_v<<<dim3(32, 64, 8), dim3(32, 8), 0, stream>>>(value, vt);

  // projections: q = query @ Wq^T + b, k = key @ Wk^T + b   (bf16 out)
  gemm256<0><<<dim3(4, 64, 1), 512, 0, stream>>>(
      qx, wq, qp, Wq_b, nullptr, 16384, 1024, 1024, 0, 0, 0);
  gemm256<0><<<dim3(4, 64, 1), 512, 0, stream>>>(
      kx, wk, kp, Wk_b, nullptr, 16384, 1024, 1024, 0, 0, 0);
  // scores: S = mask ? (q @ k^T)/32 : -1e9   (bf16 out, batched)
  gemm256<1><<<dim3(8, 8, 8), 512, 0, stream>>>(
      qp, kp, S, nullptr, mask, 2048, 2048, 1024, 2048LL * 1024,
      2048LL * 1024, 2048LL * 2048);
  softmax_rows<<<16384, 256, 0, stream>>>(S, P);
  // out = P @ V  (via V^T, f32 out, batched)
  gemm256<2><<<dim3(4, 8, 8), 512, 0, stream>>>(
      P, vt, out, nullptr, nullptr, 2048, 1024, 2048, 2048LL * 2048,
      1024LL * 2048, 2048LL * 1024);
}

// Round 3
// 492.499 us; speedup vs baseline: 1.0285x; 1.0285x over previous
//
#include <hip/hip_runtime.h>

typedef __bf16 bf16;
typedef __bf16 bf16x8 __attribute__((ext_vector_type(8)));
typedef float f32x4 __attribute__((ext_vector_type(4)));
typedef float f32x16 __attribute__((ext_vector_type(16)));

// async global->LDS, 16B per lane; LDS dest is wave-uniform base + lane*16
__device__ __forceinline__ void gl_lds16(const bf16* g, bf16* l) {
  __builtin_amdgcn_global_load_lds(
      (__attribute__((address_space(1))) void*)g,
      (__attribute__((address_space(3))) void*)l, 16, 0, 0);
}

// ---------------- fp32 -> bf16 convert, 8 elems/thread ----------------
__global__ __launch_bounds__(256) void cvt_f32_bf16(
    const float* __restrict__ src, bf16* __restrict__ dst, int n8) {
  int i = blockIdx.x * 256 + threadIdx.x;
  if (i >= n8) return;
  const float4* s4 = (const float4*)src;
  float4 a = s4[2 * i], b = s4[2 * i + 1];
  bf16x8 o = {(bf16)a.x, (bf16)a.y, (bf16)a.z, (bf16)a.w,
              (bf16)b.x, (bf16)b.y, (bf16)b.z, (bf16)b.w};
  *(bf16x8*)(dst + (size_t)i * 8) = o;
}

// ------- V [2048,1024] f32 -> VT [1024,2048] bf16, per batch ----------
__global__ __launch_bounds__(256) void transpose_v(
    const float* __restrict__ V, bf16* __restrict__ VT) {
  int b = blockIdx.z;
  const float* Vb = V + (size_t)b * 2048 * 1024;
  bf16* Tb = VT + (size_t)b * 1024 * 2048;
  __shared__ float tile[32][33];  // +1 pad: conflict-free transposed read
  int tx = threadIdx.x, ty = threadIdx.y;
  int x = blockIdx.x * 32 + tx;
  int yb = blockIdx.y * 32;
#pragma unroll
  for (int j = 0; j < 4; j++)
    tile[ty + j * 8][tx] = Vb[(size_t)(yb + ty + j * 8) * 1024 + x];
  __syncthreads();
  int xo = yb + tx;
#pragma unroll
  for (int j = 0; j < 4; j++)
    Tb[(size_t)(blockIdx.x * 32 + ty + j * 8) * 2048 + xo] =
        (bf16)tile[tx][ty + j * 8];
}

// ============== 256x256 double-buffered pipelined MFMA GEMM ===========
// C = A[M,K] * Bm[N,K]^T, bf16 in, 32x32x16 MFMA.
// 512 thr = 8 waves (2M x 4N), 128x64 per wave, acc[4][2] f32x16.
// LDS: 2 buffers of BK=64 K-tiles, A[256x64]+B[256x64] bf16 = 64KB each
//   -> 128KB. Rows are 128B (8 granules of 16B) -> full 32-bank spread.
// Swizzle (T2, HW-proven scheme): row r granule g stored at slot
//   g^(r&7); staging pre-swizzles the GLOBAL granule per lane (LDS dest
//   stays linear as global_load_lds requires). Read XORs the same key.
// Schedule (T3+T4): at top of iter t, issue ALL 8 gl_lds for tile t+1
//   (into the buffer freed by the barrier ending iter t-1), THEN
//   s_waitcnt vmcnt(8): tile t landed, t+1's 8 loads stay in flight
//   across both barriers. Never vmcnt(0) until the last tile. Compute is
//   4 kk-phases x 8 MFMA, setprio(1) around each cluster (T5).
// MODE 0: C bf16 = acc + bias[col]            (projection)
// MODE 1: C bf16 = mask[col] ? acc/32 : -1e9  (QK^T scores)
// MODE 2: C f32  = acc                        (PV output)
template <int MODE>
__global__ __launch_bounds__(512, 2) void gemm256(
    const bf16* __restrict__ A, const bf16* __restrict__ Bm,
    void* __restrict__ Cv, const float* __restrict__ bias,
    const int* __restrict__ mask, int M, int N, int K,
    long long sA, long long sB, long long sC) {
  const int b = blockIdx.z;
  const bf16* Ab = A + (long long)b * sA;
  const bf16* Bb = Bm + (long long)b * sB;

  // T1: XCD-aware swizzle over the xy tile grid (nwg % 8 == 0 by launch).
  const int nx = gridDim.x, nwg = nx * gridDim.y;
  const int orig = blockIdx.y * nx + blockIdx.x;
  const int swz = (orig & 7) * (nwg >> 3) + (orig >> 3);
  const int m0 = (swz / nx) * 256, n0 = (swz % nx) * 256;

  __shared__ __align__(16) bf16 lds[2][2][256 * 64];  // [buf][A/B][r*64+k]

  const int tid = threadIdx.x, w = tid >> 6, lane = tid & 63;
  const int wr = w >> 2, wc = w & 3;  // wave grid 2x4
  const int fr = lane & 31;           // frag row within 32-tile
  const int fh = lane >> 5;           // k-granule half selector
  const int key = lane & 7;           // swizzle key (== row&7, rows 8-aligned)
  const bf16* Aq = Ab + (long long)m0 * K;
  const bf16* Bq = Bb + (long long)n0 * K;

  f32x16 acc[4][2];
#pragma unroll
  for (int i = 0; i < 4; i++)
#pragma unroll
    for (int j = 0; j < 2; j++)
#pragma unroll
      for (int r = 0; r < 16; r++) acc[i][j][r] = 0.f;

  // ---- stage K-tile t: 8 gl_lds/thread (A 4 parts + B 4 parts) ----
  // part p covers rows [p*64, p*64+64); wave w owns 8 rows = 1KB/instr.
  const int srow = lane >> 3;                      // row within wave's 8
  const int sgsw = ((lane & 7) ^ srow) * 8;        // pre-swizzled granule
  auto stage_tile = [&](int t) {
    const int buf = t & 1;
    const long long gc = (long long)t * 64 + sgsw;
    const int r0 = w * 8 + srow;
#pragma unroll
    for (int p = 0; p < 4; p++) {
      const long long r = p * 64 + r0;
      const int dbase = (p * 64 + w * 8) * 64;     // wave-uniform, linear
      gl_lds16(Aq + r * K + gc, &lds[buf][0][dbase]);
      gl_lds16(Bq + r * K + gc, &lds[buf][1][dbase]);
    }
  };

  // ---- compute one BK=64 tile: 4 kk-phases x (6 ds_read + 8 MFMA) ----
  auto compute_tile = [&](int buf) {
    const bf16* la = &lds[buf][0][0];
    const bf16* lb = &lds[buf][1][0];
#pragma unroll
    for (int kk = 0; kk < 4; kk++) {
      const int slot = ((kk * 2 + fh) ^ key) * 8;  // swizzled granule
      bf16x8 af[4], bfr[2];
#pragma unroll
      for (int mi = 0; mi < 4; mi++)
        af[mi] = *(const bf16x8*)&la[(wr * 128 + mi * 32 + fr) * 64 + slot];
#pragma unroll
      for (int ni = 0; ni < 2; ni++)
        bfr[ni] = *(const bf16x8*)&lb[(wc * 64 + ni * 32 + fr) * 64 + slot];
      __builtin_amdgcn_s_setprio(1);
#pragma unroll
      for (int mi = 0; mi < 4; mi++)
#pragma unroll
        for (int ni = 0; ni < 2; ni++)
          acc[mi][ni] = __builtin_amdgcn_mfma_f32_32x32x16_bf16(
              af[mi], bfr[ni], acc[mi][ni], 0, 0, 0);
      __builtin_amdgcn_s_setprio(0);
    }
  };

  const int NT = K >> 6;  // BK=64 tiles
  stage_tile(0);
  for (int t = 0; t < NT; ++t) {
    if (t + 1 < NT) {
      stage_tile(t + 1);  // issue BEFORE waiting on tile t: stays in flight
      asm volatile("s_waitcnt vmcnt(8)" ::: "memory");  // tile t landed
    } else {
      asm volatile("s_waitcnt vmcnt(0)" ::: "memory");
    }
    __builtin_amdgcn_s_barrier();   // all waves' tile-t stores visible
    compute_tile(t & 1);
    __builtin_amdgcn_s_barrier();   // all waves done reading buf t&1
  }

  // C/D layout (m74/m101-verified): col=lane&31,
  // row = (reg&3) + 8*(reg>>2) + 4*(lane>>5)
  const int ecol = lane & 31, er4 = (lane >> 5) * 4;
  if constexpr (MODE == 0) {
    bf16* C = (bf16*)Cv;
#pragma unroll
    for (int ni = 0; ni < 2; ni++) {
      int col = n0 + wc * 64 + ni * 32 + ecol;
      float bv = bias[col];
#pragma unroll
      for (int mi = 0; mi < 4; mi++)
#pragma unroll
        for (int r = 0; r < 16; r++) {
          int row = m0 + wr * 128 + mi * 32 + er4 + (r & 3) + 8 * (r >> 2);
          C[(long long)row * N + col] = (bf16)(acc[mi][ni][r] + bv);
        }
    }
  } else if constexpr (MODE == 1) {
    bf16* C = (bf16*)Cv + (long long)b * sC;
    const int* mb = mask + b * 2048;
#pragma unroll
    for (int ni = 0; ni < 2; ni++) {
      int col = n0 + wc * 64 + ni * 32 + ecol;
      bool keep = mb[col] != 0;
#pragma unroll
      for (int mi = 0; mi < 4; mi++)
#pragma unroll
        for (int r = 0; r < 16; r++) {
          int row = m0 + wr * 128 + mi * 32 + er4 + (r & 3) + 8 * (r >> 2);
          C[(long long)row * N + col] =
              keep ? (bf16)(acc[mi][ni][r] * 0.03125f) : (bf16)(-1e9f);
        }
    }
  } else {
    float* C = (float*)Cv + (long long)b * sC;
#pragma unroll
    for (int ni = 0; ni < 2; ni++) {
      int col = n0 + wc * 64 + ni * 32 + ecol;
#pragma unroll
      for (int mi = 0; mi < 4; mi++)
#pragma unroll
        for (int r = 0; r < 16; r++) {
          int row = m0 + wr * 128 + mi * 32 + er4 + (r & 3) + 8 * (r >> 2);
          C[(long long)row * N + col] = acc[mi][ni][r];
        }
    }
  }
}

// ------------- row softmax: S bf16 [.,2048] -> P bf16 -----------------
__global__ __launch_bounds__(256) void softmax_rows(
    const bf16* __restrict__ S, bf16* __restrict__ P) {
  long long row = blockIdx.x;
  const bf16x8* src = (const bf16x8*)(S + row * 2048);
  int tid = threadIdx.x, w = tid >> 6, lane = tid & 63;
  bf16x8 v = src[tid];
  float f[8];
#pragma unroll
  for (int i = 0; i < 8; i++) f[i] = (float)v[i];
  float m = f[0];
#pragma unroll
  for (int i = 1; i < 8; i++) m = fmaxf(m, f[i]);
#pragma unroll
  for (int off = 32; off; off >>= 1) m = fmaxf(m, __shfl_xor(m, off, 64));
  __shared__ float redm[4], reds[4];
  if (lane == 0) redm[w] = m;
  __syncthreads();
  m = fmaxf(fmaxf(redm[0], redm[1]), fmaxf(redm[2], redm[3]));
  float e[8], s = 0.f;
#pragma unroll
  for (int i = 0; i < 8; i++) {
    e[i] = __expf(f[i] - m);
    s += e[i];
  }
#pragma unroll
  for (int off = 32; off; off >>= 1) s += __shfl_xor(s, off, 64);
  if (lane == 0) reds[w] = s;
  __syncthreads();
  s = reds[0] + reds[1] + reds[2] + reds[3];
  float inv = 1.0f / s;
  bf16x8 o;
#pragma unroll
  for (int i = 0; i < 8; i++) o[i] = (bf16)(e[i] * inv);
  *(bf16x8*)(P + row * 2048 + tid * 8) = o;
}

extern "C" void kernel_launch(void* const* d_in, const int* in_sizes, int n_in,
                              void* d_out, int out_size, void* d_ws,
                              size_t ws_size, hipStream_t stream) {
  const float* query = (const float*)d_in[0];
  const float* key_in = (const float*)d_in[1];
  const float* value = (const float*)d_in[2];
  const int* mask = (const int*)d_in[3];
  const float* Wq_w = (const float*)d_in[4];
  const float* Wq_b = (const float*)d_in[5];
  const float* Wk_w = (const float*)d_in[6];
  const float* Wk_b = (const float*)d_in[7];
  float* out = (float*)d_out;

  // workspace layout (224 MB), regions time-shared:
  //  [0,128MB):  qx(32) kx(32) wq(2) wk(2)  -> then S bf16 (64)
  //  [128,192MB): qp(32) kp(32)             -> then P bf16 (64)
  //  [192,224MB): vt bf16 (32)
  const size_t MB = 1ull << 20;
  char* base = (char*)d_ws;
  bf16* qx = (bf16*)(base + 0 * MB);
  bf16* kx = (bf16*)(base + 32 * MB);
  bf16* wq = (bf16*)(base + 64 * MB);
  bf16* wk = (bf16*)(base + 66 * MB);
  bf16* S = (bf16*)(base + 0 * MB);
  bf16* qp = (bf16*)(base + 128 * MB);
  bf16* kp = (bf16*)(base + 160 * MB);
  bf16* P = (bf16*)(base + 128 * MB);
  bf16* vt = (bf16*)(base + 192 * MB);

  cvt_f32_bf16<<<8192, 256, 0, stream>>>(query, qx, 2097152);
  cvt_f32_bf16<<<8192, 256, 0, stream>>>(key_in, kx, 2097152);
  cvt_f32_bf16<<<512, 256, 0, stream>>>(Wq_w, wq, 131072);
  cvt_f32_bf16<<<512, 256, 0, stream>>>(Wk_w, wk, 131072);
  transpose_v<<<dim3(32, 64, 8), dim3(32, 8), 0, stream>>>(value, vt);

  // projections: q = query @ Wq^T + b, k = key @ Wk^T + b   (bf16 out)
  gemm256<0><<<dim3(4, 64, 1), 512, 0, stream>>>(
      qx, wq, qp, Wq_b, nullptr, 16384, 1024, 1024, 0, 0, 0);
  gemm256<0><<<dim3(4, 64, 1), 512, 0, stream>>>(
      kx, wk, kp, Wk_b, nullptr, 16384, 1024, 1024, 0, 0, 0);
  // scores: S = mask ? (q @ k^T)/32 : -1e9   (bf16 out, batched)
  gemm256<1><<<dim3(8, 8, 8), 512, 0, stream>>>(
      qp, kp, S, nullptr, mask, 2048, 2048, 1024, 2048LL * 1024,
      2048LL * 1024, 2048LL * 2048);
  softmax_rows<<<16384, 256, 0, stream>>>(S, P);
  // out = P @ V  (via V^T, f32 out, batched)
  gemm256<2><<<dim3(4, 8, 8), 512, 0, stream>>>(
      P, vt, out, nullptr, nullptr, 2048, 1024, 2048, 2048LL * 2048,
      1024LL * 2048, 2048LL * 1024);
}

// Round 4
// 487.668 us; speedup vs baseline: 1.0387x; 1.0099x over previous
//
#include <hip/hip_runtime.h>

typedef __bf16 bf16;
typedef __bf16 bf16x8 __attribute__((ext_vector_type(8)));
typedef float f32x4 __attribute__((ext_vector_type(4)));
typedef float f32x16 __attribute__((ext_vector_type(16)));

// async global->LDS, 16B per lane; LDS dest is wave-uniform base + lane*16
__device__ __forceinline__ void gl_lds16(const bf16* g, bf16* l) {
  __builtin_amdgcn_global_load_lds(
      (__attribute__((address_space(1))) void*)g,
      (__attribute__((address_space(3))) void*)l, 16, 0, 0);
}

// ---------------- fp32 -> bf16 convert, 8 elems/thread ----------------
__global__ __launch_bounds__(256) void cvt_f32_bf16(
    const float* __restrict__ src, bf16* __restrict__ dst, int n8) {
  int i = blockIdx.x * 256 + threadIdx.x;
  if (i >= n8) return;
  const float4* s4 = (const float4*)src;
  float4 a = s4[2 * i], b = s4[2 * i + 1];
  bf16x8 o = {(bf16)a.x, (bf16)a.y, (bf16)a.z, (bf16)a.w,
              (bf16)b.x, (bf16)b.y, (bf16)b.z, (bf16)b.w};
  *(bf16x8*)(dst + (size_t)i * 8) = o;
}

// ------- V [2048,1024] f32 -> VT [1024,2048] bf16, per batch ----------
__global__ __launch_bounds__(256) void transpose_v(
    const float* __restrict__ V, bf16* __restrict__ VT) {
  int b = blockIdx.z;
  const float* Vb = V + (size_t)b * 2048 * 1024;
  bf16* Tb = VT + (size_t)b * 1024 * 2048;
  __shared__ float tile[32][33];  // +1 pad: conflict-free transposed read
  int tx = threadIdx.x, ty = threadIdx.y;
  int x = blockIdx.x * 32 + tx;
  int yb = blockIdx.y * 32;
#pragma unroll
  for (int j = 0; j < 4; j++)
    tile[ty + j * 8][tx] = Vb[(size_t)(yb + ty + j * 8) * 1024 + x];
  __syncthreads();
  int xo = yb + tx;
#pragma unroll
  for (int j = 0; j < 4; j++)
    Tb[(size_t)(blockIdx.x * 32 + ty + j * 8) * 2048 + xo] =
        (bf16)tile[tx][ty + j * 8];
}

// ============== 256x256 double-buffered pipelined MFMA GEMM ===========
// C = A[M,K] * Bm[N,K]^T, bf16 in, 32x32x16 MFMA.
// 512 thr = 8 waves (2M x 4N), 128x64 per wave, acc[4][2] f32x16.
// LDS: 2 buffers of BK=64 K-tiles (128KB) -> 1 block/CU. Fetch-path is
//   the wall (R3: 6630cy/tile vs 2048 MFMA floor; 512MB staged/dispatch).
// XCD mapping:
//   ZMAP=1 (batched GEMMs): full-3D remap, XCD c = Lid%8 computes ALL
//     tiles of batch c -> per-XCD L2 fill drops to compulsory (QK:
//     36MB->8MB per XCD). K-slice working set ~512KB << 4MB L2.
//   ZMAP=0 (projections): rect scheme, per-XCD 8m x 4n (near-compulsory).
// Swizzle (T2 + R3 quad-fix): row r granule g at slot
//   g ^ (r&7) ^ (((r>>3)&3)<<1). The extra term spreads the 4-way
//   aliasing quad {fr,fr+8,fr+16,fr+24} (R3: exactly +4cy per b128 read)
//   across 4 bank-groups. Store side: term is (w&3)<<1, wave-uniform.
// Schedule (T3+T4): issue tile t+1's 8 gl_lds, THEN vmcnt(8) (tile t
//   landed, t+1 in flight across barriers). Never vmcnt(0) mid-loop.
// MODE 0: C bf16 = acc + bias[col]            (projection)
// MODE 1: C bf16 = mask[col] ? acc/32 : -1e9  (QK^T scores)
// MODE 2: C f32  = acc                        (PV output)
template <int MODE, int ZMAP>
__global__ __launch_bounds__(512, 2) void gemm256(
    const bf16* __restrict__ A, const bf16* __restrict__ Bm,
    void* __restrict__ Cv, const float* __restrict__ bias,
    const int* __restrict__ mask, int M, int N, int K,
    long long sA, long long sB, long long sC) {
  int b, m0, n0;
  if constexpr (ZMAP == 1) {
    // batch-partitioned: XCD c owns batch c entirely (zero cross-XCD share)
    const int L = (blockIdx.z * gridDim.y + blockIdx.y) * gridDim.x +
                  blockIdx.x;
    b = L & 7;
    const int J = L >> 3;                 // tile within batch
    m0 = (J / gridDim.x) * 256;
    n0 = (J % gridDim.x) * 256;
  } else {
    // single-plane rect scheme (proven): per-XCD 8m x 4n block cluster
    b = blockIdx.z;
    const int nx = gridDim.x, nwg = nx * gridDim.y;
    const int orig = blockIdx.y * nx + blockIdx.x;
    const int swz = (orig & 7) * (nwg >> 3) + (orig >> 3);
    m0 = (swz / nx) * 256;
    n0 = (swz % nx) * 256;
  }
  const bf16* Ab = A + (long long)b * sA;
  const bf16* Bb = Bm + (long long)b * sB;

  __shared__ __align__(16) bf16 lds[2][2][256 * 64];  // [buf][A/B][r*64+k]

  const int tid = threadIdx.x, w = tid >> 6, lane = tid & 63;
  const int wr = w >> 2, wc = w & 3;  // wave grid 2x4
  const int fr = lane & 31;           // frag row within 32-tile
  const int fh = lane >> 5;           // k-granule half selector
  // read-side swizzle key: row bits 0-2 XOR (row bits 3-4)<<1
  const int key = (fr & 7) ^ (((fr >> 3) & 3) << 1);
  const bf16* Aq = Ab + (long long)m0 * K;
  const bf16* Bq = Bb + (long long)n0 * K;

  f32x16 acc[4][2];
#pragma unroll
  for (int i = 0; i < 4; i++)
#pragma unroll
    for (int j = 0; j < 2; j++)
#pragma unroll
      for (int r = 0; r < 16; r++) acc[i][j][r] = 0.f;

  // ---- stage K-tile t: 8 gl_lds/thread (A 4 parts + B 4 parts) ----
  // part p covers rows [p*64, p*64+64); wave w owns 8 rows = 1KB/instr.
  // dest row = p*64 + w*8 + srow: row&7 = srow, (row>>3)&3 = w&3.
  const int srow = lane >> 3;  // row within wave's 8
  const int sgsw = (((lane & 7) ^ srow ^ ((w & 3) << 1)) * 8);
  auto stage_tile = [&](int t) {
    const int buf = t & 1;
    const long long gc = (long long)t * 64 + sgsw;
    const int r0 = w * 8 + srow;
#pragma unroll
    for (int p = 0; p < 4; p++) {
      const long long r = p * 64 + r0;
      const int dbase = (p * 64 + w * 8) * 64;  // wave-uniform, linear
      gl_lds16(Aq + r * K + gc, &lds[buf][0][dbase]);
      gl_lds16(Bq + r * K + gc, &lds[buf][1][dbase]);
    }
  };

  // ---- compute one BK=64 tile: 4 kk-phases x (6 ds_read + 8 MFMA) ----
  auto compute_tile = [&](int buf) {
    const bf16* la = &lds[buf][0][0];
    const bf16* lb = &lds[buf][1][0];
#pragma unroll
    for (int kk = 0; kk < 4; kk++) {
      const int slot = ((kk * 2 + fh) ^ key) * 8;  // swizzled granule
      bf16x8 af[4], bfr[2];
#pragma unroll
      for (int mi = 0; mi < 4; mi++)
        af[mi] = *(const bf16x8*)&la[(wr * 128 + mi * 32 + fr) * 64 + slot];
#pragma unroll
      for (int ni = 0; ni < 2; ni++)
        bfr[ni] = *(const bf16x8*)&lb[(wc * 64 + ni * 32 + fr) * 64 + slot];
      __builtin_amdgcn_s_setprio(1);
#pragma unroll
      for (int mi = 0; mi < 4; mi++)
#pragma unroll
        for (int ni = 0; ni < 2; ni++)
          acc[mi][ni] = __builtin_amdgcn_mfma_f32_32x32x16_bf16(
              af[mi], bfr[ni], acc[mi][ni], 0, 0, 0);
      __builtin_amdgcn_s_setprio(0);
    }
  };

  const int NT = K >> 6;  // BK=64 tiles
  stage_tile(0);
  for (int t = 0; t < NT; ++t) {
    if (t + 1 < NT) {
      stage_tile(t + 1);  // issue BEFORE waiting on tile t: stays in flight
      asm volatile("s_waitcnt vmcnt(8)" ::: "memory");  // tile t landed
    } else {
      asm volatile("s_waitcnt vmcnt(0)" ::: "memory");
    }
    __builtin_amdgcn_s_barrier();  // all waves' tile-t stores visible
    compute_tile(t & 1);
    __builtin_amdgcn_s_barrier();  // all waves done reading buf t&1
  }

  // C/D layout (m74/m101-verified): col=lane&31,
  // row = (reg&3) + 8*(reg>>2) + 4*(lane>>5)
  const int ecol = lane & 31, er4 = (lane >> 5) * 4;
  if constexpr (MODE == 0) {
    bf16* C = (bf16*)Cv;
#pragma unroll
    for (int ni = 0; ni < 2; ni++) {
      int col = n0 + wc * 64 + ni * 32 + ecol;
      float bv = bias[col];
#pragma unroll
      for (int mi = 0; mi < 4; mi++)
#pragma unroll
        for (int r = 0; r < 16; r++) {
          int row = m0 + wr * 128 + mi * 32 + er4 + (r & 3) + 8 * (r >> 2);
          C[(long long)row * N + col] = (bf16)(acc[mi][ni][r] + bv);
        }
    }
  } else if constexpr (MODE == 1) {
    bf16* C = (bf16*)Cv + (long long)b * sC;
    const int* mb = mask + b * 2048;
#pragma unroll
    for (int ni = 0; ni < 2; ni++) {
      int col = n0 + wc * 64 + ni * 32 + ecol;
      bool keep = mb[col] != 0;
#pragma unroll
      for (int mi = 0; mi < 4; mi++)
#pragma unroll
        for (int r = 0; r < 16; r++) {
          int row = m0 + wr * 128 + mi * 32 + er4 + (r & 3) + 8 * (r >> 2);
          C[(long long)row * N + col] =
              keep ? (bf16)(acc[mi][ni][r] * 0.03125f) : (bf16)(-1e9f);
        }
    }
  } else {
    float* C = (float*)Cv + (long long)b * sC;
#pragma unroll
    for (int ni = 0; ni < 2; ni++) {
      int col = n0 + wc * 64 + ni * 32 + ecol;
#pragma unroll
      for (int mi = 0; mi < 4; mi++)
#pragma unroll
        for (int r = 0; r < 16; r++) {
          int row = m0 + wr * 128 + mi * 32 + er4 + (r & 3) + 8 * (r >> 2);
          C[(long long)row * N + col] = acc[mi][ni][r];
        }
    }
  }
}

// ------------- row softmax: S bf16 [.,2048] -> P bf16 -----------------
__global__ __launch_bounds__(256) void softmax_rows(
    const bf16* __restrict__ S, bf16* __restrict__ P) {
  long long row = blockIdx.x;
  const bf16x8* src = (const bf16x8*)(S + row * 2048);
  int tid = threadIdx.x, w = tid >> 6, lane = tid & 63;
  bf16x8 v = src[tid];
  float f[8];
#pragma unroll
  for (int i = 0; i < 8; i++) f[i] = (float)v[i];
  float m = f[0];
#pragma unroll
  for (int i = 1; i < 8; i++) m = fmaxf(m, f[i]);
#pragma unroll
  for (int off = 32; off; off >>= 1) m = fmaxf(m, __shfl_xor(m, off, 64));
  __shared__ float redm[4], reds[4];
  if (lane == 0) redm[w] = m;
  __syncthreads();
  m = fmaxf(fmaxf(redm[0], redm[1]), fmaxf(redm[2], redm[3]));
  float e[8], s = 0.f;
#pragma unroll
  for (int i = 0; i < 8; i++) {
    e[i] = __expf(f[i] - m);
    s += e[i];
  }
#pragma unroll
  for (int off = 32; off; off >>= 1) s += __shfl_xor(s, off, 64);
  if (lane == 0) reds[w] = s;
  __syncthreads();
  s = reds[0] + reds[1] + reds[2] + reds[3];
  float inv = 1.0f / s;
  bf16x8 o;
#pragma unroll
  for (int i = 0; i < 8; i++) o[i] = (bf16)(e[i] * inv);
  *(bf16x8*)(P + row * 2048 + tid * 8) = o;
}

extern "C" void kernel_launch(void* const* d_in, const int* in_sizes, int n_in,
                              void* d_out, int out_size, void* d_ws,
                              size_t ws_size, hipStream_t stream) {
  const float* query = (const float*)d_in[0];
  const float* key_in = (const float*)d_in[1];
  const float* value = (const float*)d_in[2];
  const int* mask = (const int*)d_in[3];
  const float* Wq_w = (const float*)d_in[4];
  const float* Wq_b = (const float*)d_in[5];
  const float* Wk_w = (const float*)d_in[6];
  const float* Wk_b = (const float*)d_in[7];
  float* out = (float*)d_out;

  // workspace layout (224 MB), regions time-shared:
  //  [0,128MB):  qx(32) kx(32) wq(2) wk(2)  -> then S bf16 (64)
  //  [128,192MB): qp(32) kp(32)             -> then P bf16 (64)
  //  [192,224MB): vt bf16 (32)
  const size_t MB = 1ull << 20;
  char* base = (char*)d_ws;
  bf16* qx = (bf16*)(base + 0 * MB);
  bf16* kx = (bf16*)(base + 32 * MB);
  bf16* wq = (bf16*)(base + 64 * MB);
  bf16* wk = (bf16*)(base + 66 * MB);
  bf16* S = (bf16*)(base + 0 * MB);
  bf16* qp = (bf16*)(base + 128 * MB);
  bf16* kp = (bf16*)(base + 160 * MB);
  bf16* P = (bf16*)(base + 128 * MB);
  bf16* vt = (bf16*)(base + 192 * MB);

  cvt_f32_bf16<<<8192, 256, 0, stream>>>(query, qx, 2097152);
  cvt_f32_bf16<<<8192, 256, 0, stream>>>(key_in, kx, 2097152);
  cvt_f32_bf16<<<512, 256, 0, stream>>>(Wq_w, wq, 131072);
  cvt_f32_bf16<<<512, 256, 0, stream>>>(Wk_w, wk, 131072);
  transpose_v<<<dim3(32, 64, 8), dim3(32, 8), 0, stream>>>(value, vt);

  // projections: q = query @ Wq^T + b, k = key @ Wk^T + b   (bf16 out)
  gemm256<0, 0><<<dim3(4, 64, 1), 512, 0, stream>>>(
      qx, wq, qp, Wq_b, nullptr, 16384, 1024, 1024, 0, 0, 0);
  gemm256<0, 0><<<dim3(4, 64, 1), 512, 0, stream>>>(
      kx, wk, kp, Wk_b, nullptr, 16384, 1024, 1024, 0, 0, 0);
  // scores: S = mask ? (q @ k^T)/32 : -1e9   (bf16 out, batched)
  gemm256<1, 1><<<dim3(8, 8, 8), 512, 0, stream>>>(
      qp, kp, S, nullptr, mask, 2048, 2048, 1024, 2048LL * 1024,
      2048LL * 1024, 2048LL * 2048);
  softmax_rows<<<16384, 256, 0, stream>>>(S, P);
  // out = P @ V  (via V^T, f32 out, batched)
  gemm256<2, 1><<<dim3(4, 8, 8), 512, 0, stream>>>(
      P, vt, out, nullptr, nullptr, 2048, 1024, 2048, 2048LL * 2048,
      1024LL * 2048, 2048LL * 1024);
}